// Round 14
// baseline (472.707 us; speedup 1.0000x reference)
//
#include <hip/hip_runtime.h>
#include <hip/hip_bf16.h>

// Switch-Transformer FFN, top-1 routing. B=4,S=4096,D=1024,F=2048,E=8.
// Pipeline: router_logits(+x->bf16) | bucketize | W1/W2 transpose->bf16 |
// grouped GEMM1 (gathered A, GELU, h bf16 dense by slot) |
// grouped GEMM2 (dense A, scale epi, scatter fp32).
// GEMM: 128x128 tile, 4 waves (64x64/wave). A-operand: DIRECT global->reg
// (no LDS round-trip), double-buffered 1 subtile ahead. B-operand: ring-4
// LDS (32KB), counted vmcnt(2)/iter certifies B(T+1) for any load order.
// 16-MFMA setprio cluster, 0-conflict B swizzle, XCD-chunked decode.

typedef __attribute__((ext_vector_type(8))) short short8;
typedef __attribute__((ext_vector_type(4))) float f32x4;

struct __align__(8) us4 { unsigned short x, y, z, w; };

__device__ __forceinline__ void gload16(const void* g, void* l) {
  __builtin_amdgcn_global_load_lds(
      (const __attribute__((address_space(1))) unsigned int*)g,
      (__attribute__((address_space(3))) unsigned int*)l, 16, 0, 0);
}

__device__ __forceinline__ unsigned short f2b(float f) {
  union { float f; unsigned u; } v; v.f = f;
  unsigned r = v.u + 0x7FFFu + ((v.u >> 16) & 1u);   // RNE
  return (unsigned short)(r >> 16);
}

// ---------------- router: logits, softmax top-1, expert id, x->bf16 ---------
__global__ __launch_bounds__(256) void router_logits(
    const float* __restrict__ x, const float* __restrict__ Wr,
    const float* __restrict__ br, float* __restrict__ wts,
    int* __restrict__ eidx, unsigned short* __restrict__ xb)
{
  const int lane = threadIdx.x & 63;
  const int wid  = threadIdx.x >> 6;
  const int t = blockIdx.x * 4 + wid;

  const float4* x4 = (const float4*)(x + (size_t)t * 1024);
  float acc[8];
#pragma unroll
  for (int e = 0; e < 8; ++e) acc[e] = 0.f;
#pragma unroll
  for (int i = 0; i < 4; ++i) {
    float4 v = x4[lane + 64 * i];
    const int d = (lane + 64 * i) * 4;
    const float* wr = Wr + (size_t)d * 8;
    float xs[4] = {v.x, v.y, v.z, v.w};
    us4 o;
    o.x = f2b(v.x); o.y = f2b(v.y); o.z = f2b(v.z); o.w = f2b(v.w);
    *(us4*)(xb + (size_t)t * 1024 + (size_t)(lane + 64 * i) * 4) = o;
#pragma unroll
    for (int j = 0; j < 4; ++j) {
      float4 w0 = *(const float4*)(wr + j * 8);
      float4 w1 = *(const float4*)(wr + j * 8 + 4);
      acc[0] += xs[j] * w0.x; acc[1] += xs[j] * w0.y;
      acc[2] += xs[j] * w0.z; acc[3] += xs[j] * w0.w;
      acc[4] += xs[j] * w1.x; acc[5] += xs[j] * w1.y;
      acc[6] += xs[j] * w1.z; acc[7] += xs[j] * w1.w;
    }
  }
#pragma unroll
  for (int e = 0; e < 8; ++e) {
    float v = acc[e];
#pragma unroll
    for (int m = 32; m; m >>= 1) v += __shfl_xor(v, m, 64);
    acc[e] = v;
  }
  if (lane == 0) {
    float lg[8];
#pragma unroll
    for (int e = 0; e < 8; ++e) lg[e] = acc[e] + br[e];
    float mx = lg[0]; int bi = 0;
#pragma unroll
    for (int e = 1; e < 8; ++e) if (lg[e] > mx) { mx = lg[e]; bi = e; }  // first-max == argmax
    float s = 0.f;
#pragma unroll
    for (int e = 0; e < 8; ++e) s += expf(lg[e] - mx);
    wts[t]  = 1.0f / s;
    eidx[t] = bi;
  }
}

// ---------------- bucketize ----------
__global__ __launch_bounds__(256) void bucketize(
    const int* __restrict__ eidx, int* __restrict__ cnt, int* __restrict__ list)
{
  __shared__ int lcnt[8], base[8];
  const int tid = threadIdx.x;
  if (tid < 8) lcnt[tid] = 0;
  __syncthreads();
  const int t = blockIdx.x * 256 + tid;
  const int e = eidx[t];
  const int lpos = atomicAdd(&lcnt[e], 1);
  __syncthreads();
  if (tid < 8) base[tid] = atomicAdd(&cnt[tid], lcnt[tid]);
  __syncthreads();
  list[e * 16384 + base[e] + lpos] = t;
}

// ---------------- W[k][n] fp32 -> Wt[n][k] bf16 ----------
__global__ __launch_bounds__(256) void transpose_cvt(
    const float* __restrict__ W, unsigned short* __restrict__ Wt, int K, int N)
{
  __shared__ float tl[64][65];
  const int e = blockIdx.z;
  const float* Wp = W + (size_t)e * K * N;
  unsigned short* Wtp = Wt + (size_t)e * K * N;
  const int k0 = blockIdx.y * 64, n0 = blockIdx.x * 64;
  const int r = threadIdx.x >> 4, c4 = (threadIdx.x & 15) * 4;
#pragma unroll
  for (int i = 0; i < 4; ++i) {
    float4 v = *(const float4*)(Wp + (size_t)(k0 + r + i * 16) * N + n0 + c4);
    tl[r + i * 16][c4 + 0] = v.x; tl[r + i * 16][c4 + 1] = v.y;
    tl[r + i * 16][c4 + 2] = v.z; tl[r + i * 16][c4 + 3] = v.w;
  }
  __syncthreads();
#pragma unroll
  for (int i = 0; i < 4; ++i) {
    const int n = r + i * 16;
    us4 o;
    o.x = f2b(tl[c4 + 0][n]); o.y = f2b(tl[c4 + 1][n]);
    o.z = f2b(tl[c4 + 2][n]); o.w = f2b(tl[c4 + 3][n]);
    *(us4*)(Wtp + (size_t)(n0 + n) * K + k0 + c4) = o;
  }
}

// ---------------- grouped GEMM: 128x128, A direct-to-reg, B ring-4 LDS ------
// LDS (33792 B): B slots 4x8KB @0; tok@32768; wt@33280.
// B swizzle (measured 0-conflict): 16B-slot c of row r holds chunk
// c^((r>>1)&3); fragment read applies the same XOR.
// Per subtile T (slot SR=T&3, stage SS=(T+2)&3; unroll x4, A regs ping-pong):
//   { prefetch A(T+1)->AN (4 global_load_dwordx4) | STG_B(T+2 -> SS) |
//     4 ds_read B frags(T, SR) | setprio(1) 16 MFMA (AC x bF) setprio(0) |
//     vmcnt(2) | s_barrier | fence }.
// Per-wave VMEM queue/iter = 4 A + 2 B = 6; end wait vmcnt(2): B(T+1)'s 2
// loads are the OLDEST of <=8 outstanding, so leaving 2 always completes
// them (certifies the LDS tile for all waves) regardless of compiler load
// order. A-register readiness is enforced by compiler-inserted waitcnt.
template <int K, int N, int EPI, int LOGNB>
__global__ __launch_bounds__(256, 3) void gemm_moe8(
    const unsigned short* __restrict__ A,    // EPI1: xb[16384][K] (token rows)
                                             // EPI2: h [16384][K] (slot rows)
    const unsigned short* __restrict__ Bt,   // [8][N][K] bf16
    const float* __restrict__ bias,          // [8][N]
    const int* __restrict__ cnt, const int* __restrict__ list,
    const float* __restrict__ wts, void* __restrict__ outp)
{
  constexpr int NT = K / 32;                 // 32 or 64: multiple of 4
  constexpr int NB = 1 << LOGNB;
  extern __shared__ char lds[];
  int*   tok_s = (int*)(lds + 32768);
  float* wt_s  = (float*)(lds + 33280);

  // ---- decode: XCD-chunked p -> (expert, mb, nb); nb fast (A-panel reuse)
  const int q = gridDim.x >> 3;
  const int p = ((int)blockIdx.x & 7) * q + ((int)blockIdx.x >> 3);
  int e = -1, pre = 0, cnte = 0, loc = p;
#pragma unroll
  for (int i = 0; i < 8; ++i) {
    const int c = cnt[i];
    const int bl = ((c + 127) >> 7) << LOGNB;
    if (e < 0) {
      if (loc < bl) { e = i; cnte = c; }
      else { loc -= bl; pre += c; }
    }
  }
  if (e < 0) return;
  const int row0 = (loc >> LOGNB) << 7;      // BM=128
  const int n0   = (loc & (NB - 1)) << 7;    // BN=128

  const int tid = threadIdx.x;
  const int lane = tid & 63, wid = tid >> 6;
  const int wr = wid >> 1, wc = wid & 1;     // wave output: rows wr*64, cols wc*64
  const int l15 = lane & 15, hi = lane >> 4;

  if (tid < 128) {
    const int s = row0 + tid;
    if (s < cnte) {
      const int t = list[e * 16384 + s];
      tok_s[tid] = t;
      wt_s[tid]  = (EPI == 2) ? wts[t] : 0.f;
    } else { tok_s[tid] = 0; wt_s[tid] = 0.f; }
  }
  __syncthreads();

  // ---- A direct-load row pointers: m-frag m, lane reads A[row][hi*8 + T*32]
  const unsigned short* aRP[4];
#pragma unroll
  for (int m = 0; m < 4; ++m) {
    const int row = wr * 64 + m * 16 + l15;
    if (EPI == 1) aRP[m] = A + (size_t)tok_s[row] * K + hi * 8;
    else          aRP[m] = A + (size_t)min(pre + row0 + row, 16383) * K + hi * 8;
  }

  // ---- B staging: issue k2 covers rows k2*64 + (tid>>2), 16B slot (tid&3)
  const int srow = tid >> 2;                 // 0..63
  const int gch  = ((tid & 3) ^ ((srow >> 1) & 3)) * 8;   // pre-swizzled chunk
  const unsigned short* bP[2];
#pragma unroll
  for (int k2 = 0; k2 < 2; ++k2)
    bP[k2] = Bt + ((size_t)e * N + n0 + k2 * 64 + srow) * K + gch;

  // ---- B fragment read base (XOR folds to per-lane constant)
  const int xo = ((hi ^ ((l15 >> 1) & 3)) << 4);
  const char* bB = lds + (size_t)(wc * 64 + l15) * 64 + xo;  // + slot*8192 + n*1024

  f32x4 acc[4][4];
#pragma unroll
  for (int m = 0; m < 4; ++m)
#pragma unroll
    for (int n = 0; n < 4; ++n) acc[m][n] = (f32x4){0.f, 0.f, 0.f, 0.f};

#define STG_B(S, T) do { _Pragma("unroll") \
    for (int k2 = 0; k2 < 2; ++k2) \
      gload16(bP[k2] + (size_t)(T) * 32, lds + (S) * 8192 + k2 * 4096 + (wid << 10)); \
  } while (0)
#define PREF_A(DST, T) do { _Pragma("unroll") \
    for (int m_ = 0; m_ < 4; ++m_) \
      DST[m_] = *(const short8*)(aRP[m_] + (size_t)(T) * 32); \
  } while (0)

  // one subtile: prefetch A(T+1)->AN, stage B(T+2), read B frags(T),
  // MFMA on AC, counted vmcnt(2), barrier, fence.
#define TILE_BODY(T, SR, SS, AC, AN) do { \
    const int Tn_ = ((T) + 1 < NT) ? (T) + 1 : NT - 1; \
    const int Ts_ = ((T) + 2 < NT) ? (T) + 2 : NT - 1; \
    PREF_A(AN, Tn_); \
    STG_B(SS, Ts_); \
    const char* bT = bB + (SR) * 8192; \
    short8 bF[4]; \
    _Pragma("unroll") \
    for (int n_ = 0; n_ < 4; ++n_) bF[n_] = *(const short8*)(bT + n_ * 1024); \
    __builtin_amdgcn_s_setprio(1); \
    _Pragma("unroll") \
    for (int m_ = 0; m_ < 4; ++m_) \
      _Pragma("unroll") \
      for (int n_ = 0; n_ < 4; ++n_) \
        acc[m_][n_] = __builtin_amdgcn_mfma_f32_16x16x32_bf16( \
            AC[m_], bF[n_], acc[m_][n_], 0, 0, 0); \
    __builtin_amdgcn_s_setprio(0); \
    asm volatile("s_waitcnt vmcnt(2)" ::: "memory");   /* certify B(T+1) */ \
    __builtin_amdgcn_s_barrier(); \
    asm volatile("" ::: "memory"); \
  } while (0)

  // ---- prologue: A(0)->aX; stage B tiles 0,1 into slots 0,1; certify B(0)
  short8 aX[4], aY[4];
  PREF_A(aX, 0);
  STG_B(0, 0);
  STG_B(1, 1);
  asm volatile("s_waitcnt vmcnt(2)" ::: "memory");   // A(0)+B(0) done, B(1) flying
  __builtin_amdgcn_s_barrier();
  asm volatile("" ::: "memory");

#pragma unroll 1
  for (int T = 0; T < NT; T += 4) {          // ring-4 slots + A ping-pong
    TILE_BODY(T,     0, 2, aX, aY);
    TILE_BODY(T + 1, 1, 3, aY, aX);
    TILE_BODY(T + 2, 2, 0, aX, aY);
    TILE_BODY(T + 3, 3, 1, aY, aX);
  }
#undef TILE_BODY
#undef STG_B
#undef PREF_A
  asm volatile("s_waitcnt vmcnt(0)" ::: "memory");   // drain dummy stages

  // ---- epilogue; C frag: col = lane&15, row = (lane>>4)*4 + r
  const int cRow0 = wr * 64 + (hi << 2);
  const int cColB = n0 + wc * 64 + l15;
  float bv[4];
#pragma unroll
  for (int nf = 0; nf < 4; ++nf) bv[nf] = bias[e * N + cColB + nf * 16];

  if (EPI == 1) {
    unsigned short* H = (unsigned short*)outp;
#pragma unroll
    for (int m = 0; m < 4; ++m)
#pragma unroll
      for (int r = 0; r < 4; ++r) {
        const int sl = cRow0 + m * 16 + r;
        if (row0 + sl < cnte) {
          const size_t rp = (size_t)(pre + row0 + sl) * N + cColB;
#pragma unroll
          for (int nf = 0; nf < 4; ++nf) {
            float v = acc[m][nf][r] + bv[nf];
            // tanh-form GELU via exp (dev <= ~1e-3 vs erf; threshold 3.4e-2)
            float u = 1.5957691216f * v * (1.0f + 0.044715f * v * v);
            float ex = __expf(u);
            float th = 1.0f - 2.0f / (ex + 1.0f);
            v = 0.5f * v * (1.0f + th);
            H[rp + nf * 16] = f2b(v);
          }
        }
      }
  } else {
    float* O = (float*)outp;
#pragma unroll
    for (int m = 0; m < 4; ++m)
#pragma unroll
      for (int r = 0; r < 4; ++r) {
        const int sl = cRow0 + m * 16 + r;
        if (row0 + sl < cnte) {
          const size_t rp = (size_t)tok_s[sl] * N + cColB;
          const float w = wt_s[sl];
#pragma unroll
          for (int nf = 0; nf < 4; ++nf)
            O[rp + nf * 16] = (acc[m][nf][r] + bv[nf]) * w;
        }
      }
  }
}

// ---------------------------------------------------------------------------
extern "C" void kernel_launch(void* const* d_in, const int* in_sizes, int n_in,
                              void* d_out, int out_size, void* d_ws, size_t ws_size,
                              hipStream_t stream) {
  const float* x  = (const float*)d_in[0];   // [4,4096,1024]
  const float* Wr = (const float*)d_in[1];   // [1024,8]
  const float* br = (const float*)d_in[2];   // [8]
  const float* W1 = (const float*)d_in[3];   // [8,1024,2048]
  const float* b1 = (const float*)d_in[4];   // [8,2048]
  const float* W2 = (const float*)d_in[5];   // [8,2048,1024]
  const float* b2 = (const float*)d_in[6];   // [8,1024]

  char* ws = (char*)d_ws;
  int*   cnt  = (int*)ws;                                  // 8 ints
  float* wts  = (float*)(ws + 256);                        // 16384 f32
  int*   eidx = (int*)(ws + 256 + 64 * 1024);              // 16384 int
  int*   list = (int*)(ws + 256 + 128 * 1024);             // 8*16384 int
  unsigned short* xb  = (unsigned short*)(ws + 1024 * 1024);     // 32 MB token rows
  unsigned short* w1t = xb  + (size_t)16384 * 1024;              // 32 MB
  unsigned short* w2t = w1t + (size_t)8 * 2048 * 1024;           // 32 MB
  unsigned short* h   = w2t + (size_t)8 * 1024 * 2048;           // 64 MB slot rows

  constexpr int LDS_BYTES = 33792;   // B ring-4 + tok/wt
  hipFuncSetAttribute((const void*)gemm_moe8<1024, 2048, 1, 4>,
                      hipFuncAttributeMaxDynamicSharedMemorySize, LDS_BYTES);
  hipFuncSetAttribute((const void*)gemm_moe8<2048, 1024, 2, 3>,
                      hipFuncAttributeMaxDynamicSharedMemorySize, LDS_BYTES);

  hipMemsetAsync(cnt, 0, 32, stream);
  router_logits<<<dim3(4096), 256, 0, stream>>>(x, Wr, br, wts, eidx, xb);
  bucketize<<<dim3(64), 256, 0, stream>>>(eidx, cnt, list);
  transpose_cvt<<<dim3(32, 16, 8), 256, 0, stream>>>(W1, w1t, 1024, 2048);
  transpose_cvt<<<dim3(16, 32, 8), 256, 0, stream>>>(W2, w2t, 2048, 1024);
  // worst-case m-blocks: sum_e ceil(cnt_e/128) <= 128+7 = 135
  // grids divisible by 8 for the XCD-chunked decode
  gemm_moe8<1024, 2048, 1, 4><<<dim3(135 * 16), 256, LDS_BYTES, stream>>>(
      xb, w1t, b1, cnt, list, wts, (void*)h);
  gemm_moe8<2048, 1024, 2, 3><<<dim3(135 * 8), 256, LDS_BYTES, stream>>>(
      h, w2t, b2, cnt, list, wts, d_out);
}

// Round 15
// 345.001 us; speedup vs baseline: 1.3702x; 1.3702x over previous
//
#include <hip/hip_runtime.h>
#include <hip/hip_bf16.h>

// Switch-Transformer FFN, top-1 routing. B=4,S=4096,D=1024,F=2048,E=8.
// Pipeline: router_logits(+x->bf16) | bucketize | W1/W2 transpose->bf16 |
// grouped GEMM1 (gathered A, GELU, h bf16 dense by slot) |
// grouped GEMM2 (dense A, scale epi, scatter fp32).
// GEMM: m201-template port. 256x256, BK=64, 8 waves (2Mx4N, wave 128x64),
// LDS dbuf-2 (A 2x32KB @0, B @65536). Per K-tile: 4 phases
// {ds-frags | half-tile stage | lgkm0 | bar | setprio 16 MFMA}; COUNTED
// vmcnt(6) once per K-tile (3 half-tiles stay in flight; never drains).
// Stage placement WAR-proven: each stage into the live buf follows the
// barrier after its target half's last reads. 0-conflict XOR swizzle.

typedef __attribute__((ext_vector_type(8))) short short8;
typedef __attribute__((ext_vector_type(4))) float f32x4;

struct __align__(8) us4 { unsigned short x, y, z, w; };

__device__ __forceinline__ void gload16(const void* g, void* l) {
  __builtin_amdgcn_global_load_lds(
      (const __attribute__((address_space(1))) unsigned int*)g,
      (__attribute__((address_space(3))) unsigned int*)l, 16, 0, 0);
}

__device__ __forceinline__ unsigned short f2b(float f) {
  union { float f; unsigned u; } v; v.f = f;
  unsigned r = v.u + 0x7FFFu + ((v.u >> 16) & 1u);   // RNE
  return (unsigned short)(r >> 16);
}

// ---------------- router: logits, softmax top-1, expert id, x->bf16 ---------
__global__ __launch_bounds__(256) void router_logits(
    const float* __restrict__ x, const float* __restrict__ Wr,
    const float* __restrict__ br, float* __restrict__ wts,
    int* __restrict__ eidx, unsigned short* __restrict__ xb)
{
  const int lane = threadIdx.x & 63;
  const int wid  = threadIdx.x >> 6;
  const int t = blockIdx.x * 4 + wid;

  const float4* x4 = (const float4*)(x + (size_t)t * 1024);
  float acc[8];
#pragma unroll
  for (int e = 0; e < 8; ++e) acc[e] = 0.f;
#pragma unroll
  for (int i = 0; i < 4; ++i) {
    float4 v = x4[lane + 64 * i];
    const int d = (lane + 64 * i) * 4;
    const float* wr = Wr + (size_t)d * 8;
    float xs[4] = {v.x, v.y, v.z, v.w};
    us4 o;
    o.x = f2b(v.x); o.y = f2b(v.y); o.z = f2b(v.z); o.w = f2b(v.w);
    *(us4*)(xb + (size_t)t * 1024 + (size_t)(lane + 64 * i) * 4) = o;
#pragma unroll
    for (int j = 0; j < 4; ++j) {
      float4 w0 = *(const float4*)(wr + j * 8);
      float4 w1 = *(const float4*)(wr + j * 8 + 4);
      acc[0] += xs[j] * w0.x; acc[1] += xs[j] * w0.y;
      acc[2] += xs[j] * w0.z; acc[3] += xs[j] * w0.w;
      acc[4] += xs[j] * w1.x; acc[5] += xs[j] * w1.y;
      acc[6] += xs[j] * w1.z; acc[7] += xs[j] * w1.w;
    }
  }
#pragma unroll
  for (int e = 0; e < 8; ++e) {
    float v = acc[e];
#pragma unroll
    for (int m = 32; m; m >>= 1) v += __shfl_xor(v, m, 64);
    acc[e] = v;
  }
  if (lane == 0) {
    float lg[8];
#pragma unroll
    for (int e = 0; e < 8; ++e) lg[e] = acc[e] + br[e];
    float mx = lg[0]; int bi = 0;
#pragma unroll
    for (int e = 1; e < 8; ++e) if (lg[e] > mx) { mx = lg[e]; bi = e; }  // first-max == argmax
    float s = 0.f;
#pragma unroll
    for (int e = 0; e < 8; ++e) s += expf(lg[e] - mx);
    wts[t]  = 1.0f / s;
    eidx[t] = bi;
  }
}

// ---------------- bucketize ----------
__global__ __launch_bounds__(256) void bucketize(
    const int* __restrict__ eidx, int* __restrict__ cnt, int* __restrict__ list)
{
  __shared__ int lcnt[8], base[8];
  const int tid = threadIdx.x;
  if (tid < 8) lcnt[tid] = 0;
  __syncthreads();
  const int t = blockIdx.x * 256 + tid;
  const int e = eidx[t];
  const int lpos = atomicAdd(&lcnt[e], 1);
  __syncthreads();
  if (tid < 8) base[tid] = atomicAdd(&cnt[tid], lcnt[tid]);
  __syncthreads();
  list[e * 16384 + base[e] + lpos] = t;
}

// ---------------- W[k][n] fp32 -> Wt[n][k] bf16 ----------
__global__ __launch_bounds__(256) void transpose_cvt(
    const float* __restrict__ W, unsigned short* __restrict__ Wt, int K, int N)
{
  __shared__ float tl[64][65];
  const int e = blockIdx.z;
  const float* Wp = W + (size_t)e * K * N;
  unsigned short* Wtp = Wt + (size_t)e * K * N;
  const int k0 = blockIdx.y * 64, n0 = blockIdx.x * 64;
  const int r = threadIdx.x >> 4, c4 = (threadIdx.x & 15) * 4;
#pragma unroll
  for (int i = 0; i < 4; ++i) {
    float4 v = *(const float4*)(Wp + (size_t)(k0 + r + i * 16) * N + n0 + c4);
    tl[r + i * 16][c4 + 0] = v.x; tl[r + i * 16][c4 + 1] = v.y;
    tl[r + i * 16][c4 + 2] = v.z; tl[r + i * 16][c4 + 3] = v.w;
  }
  __syncthreads();
#pragma unroll
  for (int i = 0; i < 4; ++i) {
    const int n = r + i * 16;
    us4 o;
    o.x = f2b(tl[c4 + 0][n]); o.y = f2b(tl[c4 + 1][n]);
    o.z = f2b(tl[c4 + 2][n]); o.w = f2b(tl[c4 + 3][n]);
    *(us4*)(Wtp + (size_t)(n0 + n) * K + k0 + c4) = o;
  }
}

// ---------------- grouped GEMM: 256x256, BK=64, 4-phase counted-vmcnt -------
// LDS (133120 B): A [buf][half][128r][64k] 2x32KB @0; B same @65536;
// tok@131072 wt@132096. Row=128B=8 chunks; chunk c of row r holds global
// chunk c^(r&7). Stage issue k2 covers rows wid*8+(lane>>3)+k2*64, phys
// slot lane&7 -> src chunk (lane&7)^(lane>>3). Quadrants per K-tile:
//   ph0: ds A m0-3 + B n0-1 (12); STG Bh1(t+1); lgkm0|bar; MFMA m03xn01
//   ph1: ds B n2-3 (4);                         lgkm0|bar; MFMA m03xn23
//   ph2: ds A m4-7 (8, reuse aF); STG Bh0(t+2); lgkm0|bar; MFMA m47xn23
//   ph3: STG Ah0+Ah1(t+2); vmcnt(6)|bar;                   MFMA m47xn01
// vmcnt(6) queue audit: 14 outstanding -> completes exactly tile t+1's 8
// loads; 3 half-tiles (6 loads) remain in flight. WAR: Bh0(t+2) after B(t)
// reads drained (ph1 bar); Ah(t+2) after A(t) reads drained (ph2 bar).
template <int K, int N, int EPI, int LOGNB>
__global__ __launch_bounds__(512, 2) void gemm_moe8(
    const unsigned short* __restrict__ A,    // EPI1: xb[16384][K] (token rows)
                                             // EPI2: h [16384][K] (slot rows)
    const unsigned short* __restrict__ Bt,   // [8][N][K] bf16
    const float* __restrict__ bias,          // [8][N]
    const int* __restrict__ cnt, const int* __restrict__ list,
    const float* __restrict__ wts, void* __restrict__ outp)
{
  constexpr int NT = K / 64;
  constexpr int NB = 1 << LOGNB;
  extern __shared__ char lds[];
  int*   tok_s = (int*)(lds + 131072);
  float* wt_s  = (float*)(lds + 132096);

  // ---- decode: XCD-chunked p -> (expert, mb, nb); nb fast (A-panel reuse)
  const int q = gridDim.x >> 3;
  const int p = ((int)blockIdx.x & 7) * q + ((int)blockIdx.x >> 3);
  int e = -1, pre = 0, cnte = 0, loc = p;
#pragma unroll
  for (int i = 0; i < 8; ++i) {
    const int c = cnt[i];
    const int bl = ((c + 255) >> 8) << LOGNB;
    if (e < 0) {
      if (loc < bl) { e = i; cnte = c; }
      else { loc -= bl; pre += c; }
    }
  }
  if (e < 0) return;
  const int row0 = (loc >> LOGNB) << 8;      // BM=256
  const int n0   = (loc & (NB - 1)) << 8;    // BN=256

  const int tid = threadIdx.x;
  const int lane = tid & 63, wid = tid >> 6;
  const int wr = wid >> 2, wc = wid & 3;     // wave output: rows wr*128, cols wc*64
  const int l15 = lane & 15, hi = lane >> 4;

  if (tid < 256) {
    const int s = row0 + tid;
    if (s < cnte) {
      const int t = list[e * 16384 + s];
      tok_s[tid] = t;
      wt_s[tid]  = (EPI == 2) ? wts[t] : 0.f;
    } else { tok_s[tid] = 0; wt_s[tid] = 0.f; }
  }
  __syncthreads();

  // ---- staging sources (verified R12 mapping)
  const int r8 = lane >> 3;
  const int ch = (lane & 7) ^ r8;            // pre-swizzled source chunk
  const unsigned short* aP[4];
  const unsigned short* bP[4];
#pragma unroll
  for (int k2 = 0; k2 < 4; ++k2) {
    const int row = wid * 8 + r8 + k2 * 64;
    if (EPI == 1) aP[k2] = A + (size_t)tok_s[row] * K + ch * 8;
    else          aP[k2] = A + (size_t)min(pre + row0 + row, 16383) * K + ch * 8;
    bP[k2] = Bt + ((size_t)e * N + n0 + row) * K + ch * 8;
  }

  // ---- fragment read bases (verified R12 math)
  const int sl0 = ((hi ^ (l15 & 7)) << 4);            // kc=0
  const int sl1 = (((4 + hi) ^ (l15 & 7)) << 4);      // kc=1
  const char* aR0 = lds + (size_t)(wr * 128 + l15) * 128 + sl0;
  const char* aR1 = lds + (size_t)(wr * 128 + l15) * 128 + sl1;
  const char* bR0 = lds + 65536 + (size_t)(wc * 64 + l15) * 128 + sl0;
  const char* bR1 = lds + 65536 + (size_t)(wc * 64 + l15) * 128 + sl1;

  f32x4 acc[8][4];
#pragma unroll
  for (int m = 0; m < 8; ++m)
#pragma unroll
    for (int n = 0; n < 4; ++n) acc[m][n] = (f32x4){0.f, 0.f, 0.f, 0.f};

  // half H of A/B: stage issues k2 = 2H, 2H+1 (2 x gload16 each)
#define STG_AH(BUF, T, H) do { _Pragma("unroll") \
    for (int k2 = 2 * (H); k2 < 2 * (H) + 2; ++k2) \
      gload16(aP[k2] + (size_t)(T) * 64, lds + (BUF) * 32768 + k2 * 8192 + (wid << 10)); \
  } while (0)
#define STG_BH(BUF, T, H) do { _Pragma("unroll") \
    for (int k2 = 2 * (H); k2 < 2 * (H) + 2; ++k2) \
      gload16(bP[k2] + (size_t)(T) * 64, lds + 65536 + (BUF) * 32768 + k2 * 8192 + (wid << 10)); \
  } while (0)
#define LGKM_BAR() do { \
    asm volatile("s_waitcnt lgkmcnt(0)" ::: "memory"); \
    __builtin_amdgcn_sched_barrier(0); \
    __builtin_amdgcn_s_barrier(); \
    asm volatile("" ::: "memory"); } while (0)

  // ---- prologue: tile0 all 4 halves (8 loads) + tile1 {Bh0,Ah0,Ah1} (6)
  STG_BH(0, 0, 0); STG_AH(0, 0, 0); STG_AH(0, 0, 1); STG_BH(0, 0, 1);
  STG_BH(1, 1, 0); STG_AH(1, 1, 0); STG_AH(1, 1, 1);
  asm volatile("s_waitcnt vmcnt(6)" ::: "memory");   // tile0 certified
  __builtin_amdgcn_s_barrier();
  asm volatile("" ::: "memory");

  short8 aF[8], bA[4], bB[4];
#pragma unroll 1
  for (int T = 0; T < NT; ++T) {
    const int buf = T & 1, bufn = buf ^ 1;
    const int Ts1 = (T + 1 < NT) ? T + 1 : NT - 1;   // dummy at tail
    const int Ts2 = (T + 2 < NT) ? T + 2 : NT - 1;
    const char* a0 = aR0 + buf * 32768;
    const char* a1 = aR1 + buf * 32768;
    const char* b0 = bR0 + buf * 32768;
    const char* b1 = bR1 + buf * 32768;

    // ---- ph0: A m0-3, B n0-1; stage Bh1(T+1); MFMA m0-3 x n0-1
#pragma unroll
    for (int m = 0; m < 4; ++m) {
      aF[2 * m]     = *(const short8*)(a0 + m * 2048);
      aF[2 * m + 1] = *(const short8*)(a1 + m * 2048);
    }
#pragma unroll
    for (int n = 0; n < 2; ++n) {
      bA[2 * n]     = *(const short8*)(b0 + n * 2048);
      bA[2 * n + 1] = *(const short8*)(b1 + n * 2048);
    }
    STG_BH(bufn, Ts1, 1);
    LGKM_BAR();
    __builtin_amdgcn_s_setprio(1);
#pragma unroll
    for (int m = 0; m < 4; ++m)
#pragma unroll
      for (int n = 0; n < 2; ++n) {
        acc[m][n] = __builtin_amdgcn_mfma_f32_16x16x32_bf16(aF[2 * m], bA[2 * n], acc[m][n], 0, 0, 0);
        acc[m][n] = __builtin_amdgcn_mfma_f32_16x16x32_bf16(aF[2 * m + 1], bA[2 * n + 1], acc[m][n], 0, 0, 0);
      }
    __builtin_amdgcn_s_setprio(0);

    // ---- ph1: B n2-3; MFMA m0-3 x n2-3
#pragma unroll
    for (int n = 0; n < 2; ++n) {
      bB[2 * n]     = *(const short8*)(b0 + (2 + n) * 2048);
      bB[2 * n + 1] = *(const short8*)(b1 + (2 + n) * 2048);
    }
    LGKM_BAR();
    __builtin_amdgcn_s_setprio(1);
#pragma unroll
    for (int m = 0; m < 4; ++m)
#pragma unroll
      for (int n = 0; n < 2; ++n) {
        acc[m][2 + n] = __builtin_amdgcn_mfma_f32_16x16x32_bf16(aF[2 * m], bB[2 * n], acc[m][2 + n], 0, 0, 0);
        acc[m][2 + n] = __builtin_amdgcn_mfma_f32_16x16x32_bf16(aF[2 * m + 1], bB[2 * n + 1], acc[m][2 + n], 0, 0, 0);
      }
    __builtin_amdgcn_s_setprio(0);

    // ---- ph2: A m4-7 (reuse aF); stage Bh0(T+2); MFMA m4-7 x n2-3
#pragma unroll
    for (int m = 0; m < 4; ++m) {
      aF[2 * m]     = *(const short8*)(a0 + (4 + m) * 2048);
      aF[2 * m + 1] = *(const short8*)(a1 + (4 + m) * 2048);
    }
    STG_BH(buf, Ts2, 0);
    LGKM_BAR();
    __builtin_amdgcn_s_setprio(1);
#pragma unroll
    for (int m = 0; m < 4; ++m)
#pragma unroll
      for (int n = 0; n < 2; ++n) {
        acc[4 + m][2 + n] = __builtin_amdgcn_mfma_f32_16x16x32_bf16(aF[2 * m], bB[2 * n], acc[4 + m][2 + n], 0, 0, 0);
        acc[4 + m][2 + n] = __builtin_amdgcn_mfma_f32_16x16x32_bf16(aF[2 * m + 1], bB[2 * n + 1], acc[4 + m][2 + n], 0, 0, 0);
      }
    __builtin_amdgcn_s_setprio(0);

    // ---- ph3: stage Ah0+Ah1(T+2); COUNTED vmcnt(6); MFMA m4-7 x n0-1
    STG_AH(buf, Ts2, 0);
    STG_AH(buf, Ts2, 1);
    asm volatile("s_waitcnt vmcnt(6)" ::: "memory");   // certify tile T+1
    __builtin_amdgcn_s_barrier();
    asm volatile("" ::: "memory");
    __builtin_amdgcn_s_setprio(1);
#pragma unroll
    for (int m = 0; m < 4; ++m)
#pragma unroll
      for (int n = 0; n < 2; ++n) {
        acc[4 + m][n] = __builtin_amdgcn_mfma_f32_16x16x32_bf16(aF[2 * m], bA[2 * n], acc[4 + m][n], 0, 0, 0);
        acc[4 + m][n] = __builtin_amdgcn_mfma_f32_16x16x32_bf16(aF[2 * m + 1], bA[2 * n + 1], acc[4 + m][n], 0, 0, 0);
      }
    __builtin_amdgcn_s_setprio(0);
  }
#undef STG_AH
#undef STG_BH
#undef LGKM_BAR
  asm volatile("s_waitcnt vmcnt(0)" ::: "memory");     // drain dummy stages

  // ---- epilogue; C frag: col = lane&15, row = (lane>>4)*4 + r
  const int cRow0 = wr * 128 + (hi << 2);
  const int cColB = n0 + wc * 64 + l15;
  float bv[4];
#pragma unroll
  for (int nf = 0; nf < 4; ++nf) bv[nf] = bias[e * N + cColB + nf * 16];

  if (EPI == 1) {
    unsigned short* H = (unsigned short*)outp;
#pragma unroll
    for (int m = 0; m < 8; ++m)
#pragma unroll
      for (int r = 0; r < 4; ++r) {
        const int sl = cRow0 + m * 16 + r;
        if (row0 + sl < cnte) {
          const size_t rp = (size_t)(pre + row0 + sl) * N + cColB;
#pragma unroll
          for (int nf = 0; nf < 4; ++nf) {
            float v = acc[m][nf][r] + bv[nf];
            // tanh-form GELU via exp (dev <= ~1e-3 vs erf; threshold 3.4e-2)
            float u = 1.5957691216f * v * (1.0f + 0.044715f * v * v);
            float ex = __expf(u);
            float th = 1.0f - 2.0f / (ex + 1.0f);
            v = 0.5f * v * (1.0f + th);
            H[rp + nf * 16] = f2b(v);
          }
        }
      }
  } else {
    float* O = (float*)outp;
#pragma unroll
    for (int m = 0; m < 8; ++m)
#pragma unroll
      for (int r = 0; r < 4; ++r) {
        const int sl = cRow0 + m * 16 + r;
        if (row0 + sl < cnte) {
          const size_t rp = (size_t)tok_s[sl] * N + cColB;
          const float w = wt_s[sl];
#pragma unroll
          for (int nf = 0; nf < 4; ++nf)
            O[rp + nf * 16] = (acc[m][nf][r] + bv[nf]) * w;
        }
      }
  }
}

// ---------------------------------------------------------------------------
extern "C" void kernel_launch(void* const* d_in, const int* in_sizes, int n_in,
                              void* d_out, int out_size, void* d_ws, size_t ws_size,
                              hipStream_t stream) {
  const float* x  = (const float*)d_in[0];   // [4,4096,1024]
  const float* Wr = (const float*)d_in[1];   // [1024,8]
  const float* br = (const float*)d_in[2];   // [8]
  const float* W1 = (const float*)d_in[3];   // [8,1024,2048]
  const float* b1 = (const float*)d_in[4];   // [8,2048]
  const float* W2 = (const float*)d_in[5];   // [8,2048,1024]
  const float* b2 = (const float*)d_in[6];   // [8,1024]

  char* ws = (char*)d_ws;
  int*   cnt  = (int*)ws;                                  // 8 ints
  float* wts  = (float*)(ws + 256);                        // 16384 f32
  int*   eidx = (int*)(ws + 256 + 64 * 1024);              // 16384 int
  int*   list = (int*)(ws + 256 + 128 * 1024);             // 8*16384 int
  unsigned short* xb  = (unsigned short*)(ws + 1024 * 1024);     // 32 MB token rows
  unsigned short* w1t = xb  + (size_t)16384 * 1024;              // 32 MB
  unsigned short* w2t = w1t + (size_t)8 * 2048 * 1024;           // 32 MB
  unsigned short* h   = w2t + (size_t)8 * 1024 * 2048;           // 64 MB slot rows

  constexpr int LDS_BYTES = 133120;   // dbuf-2 256x256 + tok/wt, 1 block/CU
  hipFuncSetAttribute((const void*)gemm_moe8<1024, 2048, 1, 3>,
                      hipFuncAttributeMaxDynamicSharedMemorySize, LDS_BYTES);
  hipFuncSetAttribute((const void*)gemm_moe8<2048, 1024, 2, 2>,
                      hipFuncAttributeMaxDynamicSharedMemorySize, LDS_BYTES);

  hipMemsetAsync(cnt, 0, 32, stream);
  router_logits<<<dim3(4096), 256, 0, stream>>>(x, Wr, br, wts, eidx, xb);
  bucketize<<<dim3(64), 256, 0, stream>>>(eidx, cnt, list);
  transpose_cvt<<<dim3(32, 16, 8), 256, 0, stream>>>(W1, w1t, 1024, 2048);
  transpose_cvt<<<dim3(16, 32, 8), 256, 0, stream>>>(W2, w2t, 2048, 1024);
  // worst-case m-blocks: sum_e ceil(cnt_e/256) <= 64+7 = 71
  // grids divisible by 8 for the XCD-chunked decode
  gemm_moe8<1024, 2048, 1, 3><<<dim3(71 * 8), 512, LDS_BYTES, stream>>>(
      xb, w1t, b1, cnt, list, wts, (void*)h);
  gemm_moe8<2048, 1024, 2, 2><<<dim3(72 * 4), 512, LDS_BYTES, stream>>>(
      h, w2t, b2, cnt, list, wts, d_out);
}

// Round 16
// 302.033 us; speedup vs baseline: 1.5651x; 1.1423x over previous
//
#include <hip/hip_runtime.h>
#include <hip/hip_bf16.h>

// Switch-Transformer FFN, top-1 routing. B=4,S=4096,D=1024,F=2048,E=8.
// Pipeline: prep(router + W1-transpose merged, independent sections) |
// bucketize | gemm1 (R13 structure + fused W2-transpose backfill blocks) |
// gemm2 (R13 structure).
// GEMM (frozen R13-best): 128x128 tile, 4 waves (64x64/wave), BK=32,
// ring-3 LDS (50KB -> 3 blocks/CU), counted vmcnt(4), single barrier/subtile,
// 0-conflict XOR swizzle, XCD-chunked nb-fast decode.

typedef __attribute__((ext_vector_type(8))) short short8;
typedef __attribute__((ext_vector_type(4))) float f32x4;

struct __align__(8) us4 { unsigned short x, y, z, w; };

__device__ __forceinline__ void gload16(const void* g, void* l) {
  __builtin_amdgcn_global_load_lds(
      (const __attribute__((address_space(1))) unsigned int*)g,
      (__attribute__((address_space(3))) unsigned int*)l, 16, 0, 0);
}

__device__ __forceinline__ unsigned short f2b(float f) {
  union { float f; unsigned u; } v; v.f = f;
  unsigned r = v.u + 0x7FFFu + ((v.u >> 16) & 1u);   // RNE
  return (unsigned short)(r >> 16);
}

// ---------------- prep: [0,4096) router | [4096,8192) W1 transpose ----------
// Sections are independent; merging lets the memory system overlap them.
__global__ __launch_bounds__(256) void prep(
    const float* __restrict__ x, const float* __restrict__ Wr,
    const float* __restrict__ br, float* __restrict__ wts,
    int* __restrict__ eidx, unsigned short* __restrict__ xb,
    const float* __restrict__ W1, unsigned short* __restrict__ w1t)
{
  const int bid = blockIdx.x;
  const int tid = threadIdx.x;

  if (bid >= 4096) {
    // ---- W1[k][n] fp32 (K=1024,N=2048) -> w1t[n][k] bf16 ----
    __shared__ float tl[64][65];
    const int lb = bid - 4096;
    const int ez = lb >> 9;                 // expert
    const int rem = lb & 511;
    const int by = rem >> 5;                // [0,16) k-tile
    const int bx = rem & 31;                // [0,32) n-tile
    const float* Wp = W1 + (size_t)ez * 1024 * 2048;
    unsigned short* Wtp = w1t + (size_t)ez * 1024 * 2048;
    const int k0 = by * 64, n0 = bx * 64;
    const int r = tid >> 4, c4 = (tid & 15) * 4;
#pragma unroll
    for (int i = 0; i < 4; ++i) {
      float4 v = *(const float4*)(Wp + (size_t)(k0 + r + i * 16) * 2048 + n0 + c4);
      tl[r + i * 16][c4 + 0] = v.x; tl[r + i * 16][c4 + 1] = v.y;
      tl[r + i * 16][c4 + 2] = v.z; tl[r + i * 16][c4 + 3] = v.w;
    }
    __syncthreads();
#pragma unroll
    for (int i = 0; i < 4; ++i) {
      const int n = r + i * 16;
      us4 o;
      o.x = f2b(tl[c4 + 0][n]); o.y = f2b(tl[c4 + 1][n]);
      o.z = f2b(tl[c4 + 2][n]); o.w = f2b(tl[c4 + 3][n]);
      *(us4*)(Wtp + (size_t)(n0 + n) * 1024 + k0 + c4) = o;
    }
    return;
  }

  // ---- router: one wave per token; logits, softmax top-1, x->bf16 ----
  const int lane = tid & 63;
  const int wid  = tid >> 6;
  const int t = bid * 4 + wid;

  const float4* x4 = (const float4*)(x + (size_t)t * 1024);
  float acc[8];
#pragma unroll
  for (int e = 0; e < 8; ++e) acc[e] = 0.f;
#pragma unroll
  for (int i = 0; i < 4; ++i) {
    float4 v = x4[lane + 64 * i];
    const int d = (lane + 64 * i) * 4;
    const float* wr = Wr + (size_t)d * 8;
    float xs[4] = {v.x, v.y, v.z, v.w};
    us4 o;
    o.x = f2b(v.x); o.y = f2b(v.y); o.z = f2b(v.z); o.w = f2b(v.w);
    *(us4*)(xb + (size_t)t * 1024 + (size_t)(lane + 64 * i) * 4) = o;
#pragma unroll
    for (int j = 0; j < 4; ++j) {
      float4 w0 = *(const float4*)(wr + j * 8);
      float4 w1 = *(const float4*)(wr + j * 8 + 4);
      acc[0] += xs[j] * w0.x; acc[1] += xs[j] * w0.y;
      acc[2] += xs[j] * w0.z; acc[3] += xs[j] * w0.w;
      acc[4] += xs[j] * w1.x; acc[5] += xs[j] * w1.y;
      acc[6] += xs[j] * w1.z; acc[7] += xs[j] * w1.w;
    }
  }
#pragma unroll
  for (int e = 0; e < 8; ++e) {
    float v = acc[e];
#pragma unroll
    for (int m = 32; m; m >>= 1) v += __shfl_xor(v, m, 64);
    acc[e] = v;
  }
  if (lane == 0) {
    float lg[8];
#pragma unroll
    for (int e = 0; e < 8; ++e) lg[e] = acc[e] + br[e];
    float mx = lg[0]; int bi = 0;
#pragma unroll
    for (int e = 1; e < 8; ++e) if (lg[e] > mx) { mx = lg[e]; bi = e; }  // first-max == argmax
    float s = 0.f;
#pragma unroll
    for (int e = 0; e < 8; ++e) s += expf(lg[e] - mx);
    wts[t]  = 1.0f / s;
    eidx[t] = bi;
  }
}

// ---------------- bucketize ----------
__global__ __launch_bounds__(256) void bucketize(
    const int* __restrict__ eidx, int* __restrict__ cnt, int* __restrict__ list)
{
  __shared__ int lcnt[8], base[8];
  const int tid = threadIdx.x;
  if (tid < 8) lcnt[tid] = 0;
  __syncthreads();
  const int t = blockIdx.x * 256 + tid;
  const int e = eidx[t];
  const int lpos = atomicAdd(&lcnt[e], 1);
  __syncthreads();
  if (tid < 8) base[tid] = atomicAdd(&cnt[tid], lcnt[tid]);
  __syncthreads();
  list[e * 16384 + base[e] + lpos] = t;
}

// ---------------- grouped GEMM: 128x128, BK=32, ring-3, 3 blocks/CU ---------
// (R13 structure, frozen.) LDS (50176 B): A slots 3x8KB @0; B slots 3x8KB
// @24576; tok@49152 wt@49664. Swizzle: 16B-slot c of row r holds chunk
// c^((r>>1)&3). Iter T: { STG A+B(T+2) | 8 ds_read frags(T) | setprio(1)
// 16 MFMA setprio(0) | vmcnt(4) | s_barrier | fence }. vmcnt(4) certifies
// tile T+1; never drains in-loop.
// TFUSE=1 (gemm1): blocks with bid >= nG do the W2[k][n]->w2t[n][k]
// transpose instead (backfill idle CU slots; reuses dynamic LDS).
template <int K, int N, int EPI, int LOGNB, int TFUSE>
__global__ __launch_bounds__(256, 4) void gemm_moe8(
    const unsigned short* __restrict__ A,    // EPI1: xb[16384][K] (token rows)
                                             // EPI2: h [16384][K] (slot rows)
    const unsigned short* __restrict__ Bt,   // [8][N][K] bf16
    const float* __restrict__ bias,          // [8][N]
    const int* __restrict__ cnt, const int* __restrict__ list,
    const float* __restrict__ wts, void* __restrict__ outp,
    int nG, const float* __restrict__ Wsrc, unsigned short* __restrict__ Wdst)
{
  constexpr int NT = K / 32;
  constexpr int NB = 1 << LOGNB;
  extern __shared__ char lds[];
  int*   tok_s = (int*)(lds + 49152);
  float* wt_s  = (float*)(lds + 49664);

  const int bid = blockIdx.x;
  const int tid = threadIdx.x;

  if (TFUSE && bid >= nG) {
    // ---- fused W2 transpose: [8][2048][1024] fp32 -> [8][1024][2048] bf16
    float* tl = (float*)lds;                 // [64][65] in dynamic LDS
    const int lb = bid - nG;                 // [0,4096)
    const int ez = lb >> 9;
    const int rem = lb & 511;
    const int by = rem >> 4;                 // [0,32) k-tile
    const int bx = rem & 15;                 // [0,16) n-tile
    const float* Wp = Wsrc + (size_t)ez * 2048 * 1024;
    unsigned short* Wtp = Wdst + (size_t)ez * 2048 * 1024;
    const int k0 = by * 64, nn0 = bx * 64;
    const int r = tid >> 4, c4 = (tid & 15) * 4;
#pragma unroll
    for (int i = 0; i < 4; ++i) {
      float4 v = *(const float4*)(Wp + (size_t)(k0 + r + i * 16) * 1024 + nn0 + c4);
      tl[(r + i * 16) * 65 + c4 + 0] = v.x; tl[(r + i * 16) * 65 + c4 + 1] = v.y;
      tl[(r + i * 16) * 65 + c4 + 2] = v.z; tl[(r + i * 16) * 65 + c4 + 3] = v.w;
    }
    __syncthreads();
#pragma unroll
    for (int i = 0; i < 4; ++i) {
      const int n = r + i * 16;
      us4 o;
      o.x = f2b(tl[(c4 + 0) * 65 + n]); o.y = f2b(tl[(c4 + 1) * 65 + n]);
      o.z = f2b(tl[(c4 + 2) * 65 + n]); o.w = f2b(tl[(c4 + 3) * 65 + n]);
      *(us4*)(Wtp + (size_t)(nn0 + n) * 2048 + k0 + c4) = o;
    }
    return;
  }

  // ---- decode: XCD-chunked p -> (expert, mb, nb); nb fast (A-panel reuse)
  const int q = nG >> 3;
  const int p = (bid & 7) * q + (bid >> 3);
  int e = -1, pre = 0, cnte = 0, loc = p;
#pragma unroll
  for (int i = 0; i < 8; ++i) {
    const int c = cnt[i];
    const int bl = ((c + 127) >> 7) << LOGNB;
    if (e < 0) {
      if (loc < bl) { e = i; cnte = c; }
      else { loc -= bl; pre += c; }
    }
  }
  if (e < 0) return;
  const int row0 = (loc >> LOGNB) << 7;      // BM=128
  const int n0   = (loc & (NB - 1)) << 7;    // BN=128

  const int lane = tid & 63, wid = tid >> 6;
  const int wr = wid >> 1, wc = wid & 1;     // wave output: rows wr*64, cols wc*64
  const int l15 = lane & 15;

  if (tid < 128) {
    const int s = row0 + tid;
    if (s < cnte) {
      const int t = list[e * 16384 + s];
      tok_s[tid] = t;
      wt_s[tid]  = (EPI == 2) ? wts[t] : 0.f;
    } else { tok_s[tid] = 0; wt_s[tid] = 0.f; }
  }
  __syncthreads();

  // ---- staging: issue k2 covers rows k2*64 + (tid>>2), 16B slot (tid&3)
  const int srow = tid >> 2;                 // 0..63
  const int gch  = ((tid & 3) ^ ((srow >> 1) & 3)) * 8;   // pre-swizzled chunk
  const unsigned short* aP[2];
  const unsigned short* bP[2];
#pragma unroll
  for (int k2 = 0; k2 < 2; ++k2) {
    const int row = k2 * 64 + srow;
    if (EPI == 1) aP[k2] = A + (size_t)tok_s[row] * K + gch;
    else          aP[k2] = A + (size_t)min(pre + row0 + row, 16383) * K + gch;
    bP[k2] = Bt + ((size_t)e * N + n0 + row) * K + gch;
  }

  // ---- fragment read bases (XOR folds to per-lane constant)
  const int xo = (((lane >> 4) ^ ((l15 >> 1) & 3)) << 4);
  const char* aB = lds + (size_t)(wr * 64 + l15) * 64 + xo;          // + slot*8192 + m*1024
  const char* bB = lds + 24576 + (size_t)(wc * 64 + l15) * 64 + xo;  // + slot*8192 + n*1024

  f32x4 acc[4][4];
#pragma unroll
  for (int m = 0; m < 4; ++m)
#pragma unroll
    for (int n = 0; n < 4; ++n) acc[m][n] = (f32x4){0.f, 0.f, 0.f, 0.f};

#define STG_A(S, T) do { _Pragma("unroll") \
    for (int k2 = 0; k2 < 2; ++k2) \
      gload16(aP[k2] + (size_t)(T) * 32, lds + (S) * 8192 + k2 * 4096 + (wid << 10)); \
  } while (0)
#define STG_B(S, T) do { _Pragma("unroll") \
    for (int k2 = 0; k2 < 2; ++k2) \
      gload16(bP[k2] + (size_t)(T) * 32, lds + 24576 + (S) * 8192 + k2 * 4096 + (wid << 10)); \
  } while (0)

  // one subtile: stage tile T+2 into SS, read slot SR, MFMA, vmcnt(4), bar
#define TILE_BODY(T, SR, SS) do { \
    const int Ts_ = ((T) + 2 < NT) ? (T) + 2 : NT - 1;   /* dummy at tail */ \
    STG_A(SS, Ts_); \
    STG_B(SS, Ts_); \
    const char* aT = aB + (SR) * 8192; \
    const char* bT = bB + (SR) * 8192; \
    short8 aF[4], bF[4]; \
    _Pragma("unroll") \
    for (int m_ = 0; m_ < 4; ++m_) aF[m_] = *(const short8*)(aT + m_ * 1024); \
    _Pragma("unroll") \
    for (int n_ = 0; n_ < 4; ++n_) bF[n_] = *(const short8*)(bT + n_ * 1024); \
    __builtin_amdgcn_s_setprio(1); \
    _Pragma("unroll") \
    for (int m_ = 0; m_ < 4; ++m_) \
      _Pragma("unroll") \
      for (int n_ = 0; n_ < 4; ++n_) \
        acc[m_][n_] = __builtin_amdgcn_mfma_f32_16x16x32_bf16( \
            aF[m_], bF[n_], acc[m_][n_], 0, 0, 0); \
    __builtin_amdgcn_s_setprio(0); \
    asm volatile("s_waitcnt vmcnt(4)" ::: "memory");   /* certify tile T+1 */ \
    __builtin_amdgcn_s_barrier(); \
    asm volatile("" ::: "memory");   /* no ds_read hoists above barrier */ \
  } while (0)

  // ---- prologue: stage tiles 0,1 into slots 0,1; certify tile 0
  STG_A(0, 0); STG_B(0, 0);
  STG_A(1, 1); STG_B(1, 1);
  asm volatile("s_waitcnt vmcnt(4)" ::: "memory");   // tile 0 landed
  __builtin_amdgcn_s_barrier();
  asm volatile("" ::: "memory");

#pragma unroll 1
  for (int T = 0; T < NT; T += 3) {                  // slots compile-time
    TILE_BODY(T, 0, 2);
    if (T + 1 < NT) TILE_BODY(T + 1, 1, 0);
    if (T + 2 < NT) TILE_BODY(T + 2, 2, 1);
  }
#undef TILE_BODY
#undef STG_A
#undef STG_B
  asm volatile("s_waitcnt vmcnt(0)" ::: "memory");   // drain dummy stages

  // ---- epilogue; C frag: col = lane&15, row = (lane>>4)*4 + r
  const int cRow0 = wr * 64 + ((lane >> 4) << 2);
  const int cColB = n0 + wc * 64 + l15;
  float bv[4];
#pragma unroll
  for (int nf = 0; nf < 4; ++nf) bv[nf] = bias[e * N + cColB + nf * 16];

  if (EPI == 1) {
    unsigned short* H = (unsigned short*)outp;
#pragma unroll
    for (int m = 0; m < 4; ++m)
#pragma unroll
      for (int r = 0; r < 4; ++r) {
        const int sl = cRow0 + m * 16 + r;
        if (row0 + sl < cnte) {
          const size_t rp = (size_t)(pre + row0 + sl) * N + cColB;
#pragma unroll
          for (int nf = 0; nf < 4; ++nf) {
            float v = acc[m][nf][r] + bv[nf];
            // tanh-form GELU via exp (dev <= ~1e-3 vs erf; threshold 3.4e-2)
            float u = 1.5957691216f * v * (1.0f + 0.044715f * v * v);
            float ex = __expf(u);
            float th = 1.0f - 2.0f / (ex + 1.0f);
            v = 0.5f * v * (1.0f + th);
            H[rp + nf * 16] = f2b(v);
          }
        }
      }
  } else {
    float* O = (float*)outp;
#pragma unroll
    for (int m = 0; m < 4; ++m)
#pragma unroll
      for (int r = 0; r < 4; ++r) {
        const int sl = cRow0 + m * 16 + r;
        if (row0 + sl < cnte) {
          const size_t rp = (size_t)tok_s[sl] * N + cColB;
          const float w = wt_s[sl];
#pragma unroll
          for (int nf = 0; nf < 4; ++nf)
            O[rp + nf * 16] = (acc[m][nf][r] + bv[nf]) * w;
        }
      }
  }
}

// ---------------------------------------------------------------------------
extern "C" void kernel_launch(void* const* d_in, const int* in_sizes, int n_in,
                              void* d_out, int out_size, void* d_ws, size_t ws_size,
                              hipStream_t stream) {
  const float* x  = (const float*)d_in[0];   // [4,4096,1024]
  const float* Wr = (const float*)d_in[1];   // [1024,8]
  const float* br = (const float*)d_in[2];   // [8]
  const float* W1 = (const float*)d_in[3];   // [8,1024,2048]
  const float* b1 = (const float*)d_in[4];   // [8,2048]
  const float* W2 = (const float*)d_in[5];   // [8,2048,1024]
  const float* b2 = (const float*)d_in[6];   // [8,1024]

  char* ws = (char*)d_ws;
  int*   cnt  = (int*)ws;                                  // 8 ints
  float* wts  = (float*)(ws + 256);                        // 16384 f32
  int*   eidx = (int*)(ws + 256 + 64 * 1024);              // 16384 int
  int*   list = (int*)(ws + 256 + 128 * 1024);             // 8*16384 int
  unsigned short* xb  = (unsigned short*)(ws + 1024 * 1024);     // 32 MB token rows
  unsigned short* w1t = xb  + (size_t)16384 * 1024;              // 32 MB
  unsigned short* w2t = w1t + (size_t)8 * 2048 * 1024;           // 32 MB
  unsigned short* h   = w2t + (size_t)8 * 1024 * 2048;           // 64 MB slot rows

  constexpr int LDS_BYTES = 50176;   // ring-3 128^2 + tok/wt -> 3 blocks/CU
  hipFuncSetAttribute((const void*)gemm_moe8<1024, 2048, 1, 4, 1>,
                      hipFuncAttributeMaxDynamicSharedMemorySize, LDS_BYTES);
  hipFuncSetAttribute((const void*)gemm_moe8<2048, 1024, 2, 3, 0>,
                      hipFuncAttributeMaxDynamicSharedMemorySize, LDS_BYTES);

  hipMemsetAsync(cnt, 0, 32, stream);
  // prep: router (4096 blocks) + W1 transpose (4096 blocks), independent
  prep<<<dim3(8192), 256, 0, stream>>>(x, Wr, br, wts, eidx, xb, W1, w1t);
  bucketize<<<dim3(64), 256, 0, stream>>>(eidx, cnt, list);
  // gemm1 (2160 GEMM blocks, /8 for XCD decode) + 4096 fused W2-transpose
  // backfill blocks. worst-case m-blocks: sum_e ceil(cnt_e/128) <= 128+7=135.
  gemm_moe8<1024, 2048, 1, 4, 1><<<dim3(135 * 16 + 4096), 256, LDS_BYTES, stream>>>(
      xb, w1t, b1, cnt, list, wts, (void*)h, 135 * 16, W2, w2t);
  gemm_moe8<2048, 1024, 2, 3, 0><<<dim3(135 * 8), 256, LDS_BYTES, stream>>>(
      h, w2t, b2, cnt, list, wts, d_out, 135 * 8, nullptr, nullptr);
}